// Round 13
// baseline (71.830 us; speedup 1.0000x reference)
//
#include <hip/hip_runtime.h>
#include <hip/hip_bf16.h>
#include <stdint.h>

#define MB_ 16384
#define NN_ 1024
#define KK_ 1024

typedef __bf16 bhalf;
typedef __bf16 bhalf8 __attribute__((ext_vector_type(8)));
typedef __bf16 bhalf4 __attribute__((ext_vector_type(4)));
typedef float f32x4 __attribute__((ext_vector_type(4)));

typedef const __attribute__((address_space(1))) void* gas_ptr;
typedef __attribute__((address_space(3))) void* las_ptr;

__device__ __forceinline__ void gload_lds16(const void* g, void* l) {
  __builtin_amdgcn_global_load_lds((gas_ptr)g, (las_ptr)l, 16, 0, 0);
}

// ---------------- K1a: partial column max / sumexp (over rows, per column) ----------------
__global__ void k_colpart(const float* __restrict__ W,
                          float* __restrict__ pM, float* __restrict__ pS) {
  int col = blockIdx.x * 256 + threadIdx.x;
  int rc  = blockIdx.y;
  const float* p = W + (size_t)rc * 32 * NN_ + col;
  float v[32];
#pragma unroll
  for (int i = 0; i < 32; ++i) v[i] = p[(size_t)i * NN_];
  float m = v[0];
#pragma unroll
  for (int i = 1; i < 32; ++i) m = fmaxf(m, v[i]);
  float s = 0.f;
#pragma unroll
  for (int i = 0; i < 32; ++i) s += __expf(v[i] - m);
  pM[rc * NN_ + col] = m;
  pS[rc * NN_ + col] = s;
}

// ---------------- K1b: combine partials -> colLSE ----------------
__global__ void k_colfin(const float* __restrict__ pM, const float* __restrict__ pS,
                         float* __restrict__ colLSE) {
  int col = blockIdx.x * 256 + threadIdx.x;
  float m = -1e30f;
#pragma unroll
  for (int i = 0; i < 32; ++i) m = fmaxf(m, pM[i * NN_ + col]);
  float s = 0.f;
#pragma unroll
  for (int i = 0; i < 32; ++i) s += pS[i * NN_ + col] * __expf(pM[i * NN_ + col] - m);
  colLSE[col] = m + __logf(s);
}

// ---------------- K2: eA[i,k] = exp(W[i,k]-colLSE[k]) ----------------
__global__ void k_expA(const float* __restrict__ W, const float* __restrict__ colLSE,
                       bhalf* __restrict__ eA) {
  int i = blockIdx.x;
  int l = threadIdx.x;
  const float4* row = (const float4*)(W + (size_t)i * NN_);
  const float4* cls = (const float4*)colLSE;
#pragma unroll
  for (int t = 0; t < 4; ++t) {
    float4 wv = row[t * 64 + l];
    float4 cv = cls[t * 64 + l];
    bhalf4 o;
    o[0] = (bhalf)__expf(wv.x - cv.x);
    o[1] = (bhalf)__expf(wv.y - cv.y);
    o[2] = (bhalf)__expf(wv.z - cv.z);
    o[3] = (bhalf)__expf(wv.w - cv.w);
    *(bhalf4*)(eA + (size_t)i * NN_ + t * 256 + l * 4) = o;
  }
}

// ---------------- GEMM: out[b,i] = log( sum_k exp(la[b,k]) * eA[i,k] ) ----------------
// 128x128 tile, BK=64, 256 thr (4 waves 2Mx2N), LDS 64KB -> 2 BLOCKS/CU (two
// independent barrier domains per CU). Round-11 schedule verbatim (16 K-tiles,
// 2 barriers/tile, STB after mid-barrier, VMW(4) steady / VMW(0) at T14):
//   top: 10 ds_read (af q0 2 + bq 8) -> lgkm0 -> MFMA q0 (8)
//   MID SBAR -> STB B(t+2) (4 gload_lds) -> af q1; VMW(4) -> cvt H0; MFMA q1
//   af q2; cvt H1; MFMA q2
//   af q3; LOADA A(t+2) (8 dwordx4); MFMA q3; END SBAR
// Steady queue at VMW: [B(t+1)4, A(t+1)8, B(t+2)4] -> VMW(4) retires B(t+1)+A(t+1).
// LDS: A dbuf [0,32K), B dbuf [32K,64K); both-sides XOR swizzle (proven geometry:
// A-load & cvt use 16-lanes-per-row; B linear-dest + pre-swizzled source).

#define VMW(N)  asm volatile("s_waitcnt vmcnt(" #N ")" ::: "memory")
#define LGKM0   asm volatile("s_waitcnt lgkmcnt(0)" ::: "memory")
#define SBAR    __builtin_amdgcn_s_barrier()
#define SCB0    __builtin_amdgcn_sched_barrier(0)
#define NOPS    ((void)0)

// B: 16KB/tile = 4 gload_lds16/thread. dest row = call*32 + (tid>>3), chunk tid&7;
// source chunk pre-swizzled: (tid&7) ^ ((tid>>3)&7).
#define STB(BUF, TOFF) do {                                                   \
    const bhalf* g_ = pgB + (TOFF) * 64;                                      \
    unsigned char* d_ = lds + 32768 + (BUF) * 16384 + tid * 16;               \
    gload_lds16(g_,            d_);                                           \
    gload_lds16(g_ + 32 * KK_, d_ + 4096);                                    \
    gload_lds16(g_ + 64 * KK_, d_ + 8192);                                    \
    gload_lds16(g_ + 96 * KK_, d_ + 12288); } while (0)

// A: 32KB f32/tile, 8 coalesced dwordx4/thread. Round r_: lanes 0..15 cover one
// row's 256B; rows r_*16 + (tid>>4).
#define LOADA(TOFF) do {                                                      \
    _Pragma("unroll")                                                         \
    for (int r_ = 0; r_ < 8; ++r_) va[r_] = pLA4[r_ * 4096 + (TOFF) * 16];    \
  } while (0)

// exp + pack to bf16, 4x ds_write_b64 for round-half H (rounds 4H..4H+3)
#define CVTA_H(BUF, H) do {                                                   \
    unsigned char* d_ = dA_base + (BUF) * 16384 + (H) * 8192;                 \
    _Pragma("unroll")                                                         \
    for (int j_ = 0; j_ < 4; ++j_) {                                          \
      float4 u_ = va[(H) * 4 + j_];                                           \
      bhalf4 o_;                                                              \
      o_[0] = (bhalf)__expf(u_.x); o_[1] = (bhalf)__expf(u_.y);               \
      o_[2] = (bhalf)__expf(u_.z); o_[3] = (bhalf)__expf(u_.w);               \
      *(bhalf4*)(d_ + j_ * 2048) = o_;                                        \
    } } while (0)

// af for m-frag Q (row = wr*64 + Q*16 + (l&15)), kk = 0/1
#define DS_AF(BUF, Q)                                                         \
  af[0] = *(const bhalf8*)(pA0 + (BUF) * 16384 + (Q) * 2048);                 \
  af[1] = *(const bhalf8*)(pA1 + (BUF) * 16384 + (Q) * 2048);

#define DS_BQ(BUF)                                                            \
  _Pragma("unroll")                                                           \
  for (int n_ = 0; n_ < 4; ++n_) {                                            \
    bq[n_][0] = *(const bhalf8*)(pB0 + (BUF) * 16384 + n_ * 2048);            \
    bq[n_][1] = *(const bhalf8*)(pB1 + (BUF) * 16384 + n_ * 2048);            \
  }

#define MFMA8(Q)                                                              \
  __builtin_amdgcn_s_setprio(1);                                              \
  _Pragma("unroll")                                                           \
  for (int n_ = 0; n_ < 4; ++n_)                                              \
    _Pragma("unroll")                                                         \
    for (int kk_ = 0; kk_ < 2; ++kk_)                                         \
      acc[Q][n_] = __builtin_amdgcn_mfma_f32_16x16x32_bf16(                   \
          af[kk_], bq[n_][kk_], acc[Q][n_], 0, 0, 0);                         \
  __builtin_amdgcn_s_setprio(0);

// LT: A(t+2) offset rel. base (-1 none). BT: B(t+2) offset (-1 none).
// WA: wait before cvt H0 (VMW(4)/VMW(0)/NOPS). CV: cvt A(t+1) -> buf BUF^1.
#define KTILE(BUF, LT, BT, WA, CV)                                            \
  {                                                                           \
    bhalf8 bq[4][2];                                                          \
    bhalf8 af[2];                                                             \
    DS_AF(BUF, 0) DS_BQ(BUF)                                                  \
    SCB0; LGKM0; SCB0;                                                        \
    MFMA8(0)                                                                  \
    SCB0; SBAR;                                                               \
    if ((BT) >= 0) STB(BUF, BT);                                              \
    DS_AF(BUF, 1)                                                             \
    WA;                                                                       \
    if (CV) CVTA_H((BUF) ^ 1, 0);                                             \
    LGKM0; SCB0;                                                              \
    MFMA8(1)                                                                  \
    DS_AF(BUF, 2)                                                             \
    if (CV) CVTA_H((BUF) ^ 1, 1);                                             \
    LGKM0; SCB0;                                                              \
    MFMA8(2)                                                                  \
    DS_AF(BUF, 3)                                                             \
    if ((LT) >= 0) LOADA(LT);                                                 \
    LGKM0; SCB0;                                                              \
    MFMA8(3)                                                                  \
    SCB0; SBAR;                                                               \
  }

__global__ __launch_bounds__(256, 2) void k_gemm(const float* __restrict__ LA, // [M][K] f32
                                                 const bhalf* __restrict__ Bt, // eA [N][K]
                                                 float* __restrict__ out) {
  __shared__ __align__(16) unsigned char lds[65536];

  const int nwg = gridDim.x;              // 1024, %8==0
  const int wg  = blockIdx.x;
  const int swz = (wg & 7) * (nwg >> 3) + (wg >> 3);
  const int bm = swz >> 3;                // 0..127
  const int bn = swz & 7;                 // 0..7 (8 bn-blocks share A-panel, same XCD)

  const int tid = threadIdx.x;
  const int l = tid & 63;
  const int w = tid >> 6;
  const int wr = w >> 1;                  // 0..1 (M)
  const int wc = w & 1;                   // 0..1 (N)

  // B staging source (pre-swizzled)
  const bhalf* pgB = Bt + (size_t)(bn * 128 + (tid >> 3)) * KK_ +
                     (((tid & 7) ^ ((tid >> 3) & 7)) << 3);

  // A staging: round r_: row = r_*16 + (tid>>4), 16B chunk tid&15 (coalesced 256B rows)
  const float4* pLA4 = (const float4*)(LA + (size_t)(bm * 128 + (tid >> 4)) * KK_) + (tid & 15);
  // cvt write: row&7 == (tid>>4)&7 (round-invariant); chunk c=(tid&15)>>1, byte (tid&1)*8
  unsigned char* dA_base = lds + (tid >> 4) * 128 +
                           ((((tid & 15) >> 1) ^ ((tid >> 4) & 7)) << 4) + ((tid & 1) << 3);

  // loop-invariant LDS read bases (fragment row % 8 == l % 8)
  const int kx  = 16 * (l >> 4);
  const int x16 = (l & 7) << 4;
  const int kx0 = kx ^ x16;
  const int kx1 = (64 + kx) ^ x16;
  const unsigned char* pA0 = lds + (wr * 64 + (l & 15)) * 128 + kx0;
  const unsigned char* pA1 = lds + (wr * 64 + (l & 15)) * 128 + kx1;
  const unsigned char* pB0 = lds + 32768 + (wc * 64 + (l & 15)) * 128 + kx0;
  const unsigned char* pB1 = lds + 32768 + (wc * 64 + (l & 15)) * 128 + kx1;

  f32x4 zero = {0.f, 0.f, 0.f, 0.f};
  f32x4 acc[4][4];
#pragma unroll
  for (int m = 0; m < 4; ++m)
#pragma unroll
    for (int n = 0; n < 4; ++n) acc[m][n] = zero;

  float4 va[8];

  // prologue (queue oldest->newest): A(0)8, B(0)4 -> VMW(4) retires A(0) -> cvt buf0;
  // then B(1)4, A(1)8 -> VMW(12) retires B(0). Entering tile 0: [B(1)4, A(1)8].
  LOADA(0);
  STB(0, 0);
  VMW(4);
  CVTA_H(0, 0); CVTA_H(0, 1);
  STB(1, 1);
  LOADA(1);
  VMW(12);
  LGKM0;
  SBAR;

  // tiles 0..13: 7 pairs; base advances 2 k-tiles per pair. VMW(4) uniform.
  for (int p = 0; p < 7; ++p) {
    KTILE(0, 2, 2, VMW(4), 1)
    KTILE(1, 3, 3, VMW(4), 1)
    pLA4 += 32;   // 2 tiles * 16 float4
    pgB  += 128;  // 2 tiles * 64 bf16
  }
  // T14: queue = [B(15)4, A(15)8]; VMW(0) drains all; cvt A(15)->buf1
  KTILE(0, -1, -1, VMW(0), 1)
  // T15: pure compute
  KTILE(1, -1, -1, NOPS, 0)

  // epilogue: out = log(acc). D row = 4*(l>>4)+r (+16/mf), col = l&15 (+16/nf)
  const int c0 = bn * 128 + wc * 64 + (l & 15);
  const int r0 = bm * 128 + wr * 64 + (l >> 4) * 4;
#pragma unroll
  for (int mf = 0; mf < 4; ++mf) {
#pragma unroll
    for (int r = 0; r < 4; ++r) {
      const int row = r0 + mf * 16 + r;
      float* o = out + (size_t)row * NN_ + c0;
#pragma unroll
      for (int nf = 0; nf < 4; ++nf)
        o[nf * 16] = __logf(acc[mf][nf][r]);
    }
  }
}

extern "C" void kernel_launch(void* const* d_in, const int* in_sizes, int n_in,
                              void* d_out, int out_size, void* d_ws, size_t ws_size,
                              hipStream_t stream) {
  const float* log_alpha = (const float*)d_in[0];  // [16384,1024] f32
  const float* W         = (const float*)d_in[1];  // [1024,1024] f32
  float* out = (float*)d_out;                      // [16384,1024] f32

  uintptr_t ws = (uintptr_t)d_ws;
  bhalf* eA     = (bhalf*)(ws);                    // 2,097,152 B
  float* colLSE = (float*)(ws + 2097152);          //     4,096 B
  float* pM     = (float*)(ws + 2101248);          //   131,072 B
  float* pS     = (float*)(ws + 2232320);          //   131,072 B

  k_colpart<<<dim3(4, 32), 256, 0, stream>>>(W, pM, pS);
  k_colfin<<<4, 256, 0, stream>>>(pM, pS, colLSE);
  k_expA<<<NN_, 64, 0, stream>>>(W, colLSE, eA);
  k_gemm<<<(MB_ / 128) * (NN_ / 128), 256, 0, stream>>>(log_alpha, eA, out);
}

// Round 14
// 61.451 us; speedup vs baseline: 1.1689x; 1.1689x over previous
//
#include <hip/hip_runtime.h>
#include <hip/hip_bf16.h>
#include <stdint.h>

#define MB_ 16384
#define NN_ 1024
#define KK_ 1024

typedef __bf16 bhalf;
typedef __bf16 bhalf8 __attribute__((ext_vector_type(8)));
typedef __bf16 bhalf4 __attribute__((ext_vector_type(4)));
typedef float f32x4 __attribute__((ext_vector_type(4)));

typedef const __attribute__((address_space(1))) void* gas_ptr;
typedef __attribute__((address_space(3))) void* las_ptr;

__device__ __forceinline__ void gload_lds16(const void* g, void* l) {
  __builtin_amdgcn_global_load_lds((gas_ptr)g, (las_ptr)l, 16, 0, 0);
}

// ---------------- K1a: partial column max / sumexp (over rows, per column) ----------------
__global__ void k_colpart(const float* __restrict__ W,
                          float* __restrict__ pM, float* __restrict__ pS) {
  int col = blockIdx.x * 256 + threadIdx.x;
  int rc  = blockIdx.y;
  const float* p = W + (size_t)rc * 32 * NN_ + col;
  float v[32];
#pragma unroll
  for (int i = 0; i < 32; ++i) v[i] = p[(size_t)i * NN_];
  float m = v[0];
#pragma unroll
  for (int i = 1; i < 32; ++i) m = fmaxf(m, v[i]);
  float s = 0.f;
#pragma unroll
  for (int i = 0; i < 32; ++i) s += __expf(v[i] - m);
  pM[rc * NN_ + col] = m;
  pS[rc * NN_ + col] = s;
}

// ---------------- K1b: combine partials -> colLSE ----------------
__global__ void k_colfin(const float* __restrict__ pM, const float* __restrict__ pS,
                         float* __restrict__ colLSE) {
  int col = blockIdx.x * 256 + threadIdx.x;
  float m = -1e30f;
#pragma unroll
  for (int i = 0; i < 32; ++i) m = fmaxf(m, pM[i * NN_ + col]);
  float s = 0.f;
#pragma unroll
  for (int i = 0; i < 32; ++i) s += pS[i * NN_ + col] * __expf(pM[i * NN_ + col] - m);
  colLSE[col] = m + __logf(s);
}

// ---------------- K2: eA[i,k] = exp(W[i,k]-colLSE[k]) ----------------
__global__ void k_expA(const float* __restrict__ W, const float* __restrict__ colLSE,
                       bhalf* __restrict__ eA) {
  int i = blockIdx.x;
  int l = threadIdx.x;
  const float4* row = (const float4*)(W + (size_t)i * NN_);
  const float4* cls = (const float4*)colLSE;
#pragma unroll
  for (int t = 0; t < 4; ++t) {
    float4 wv = row[t * 64 + l];
    float4 cv = cls[t * 64 + l];
    bhalf4 o;
    o[0] = (bhalf)__expf(wv.x - cv.x);
    o[1] = (bhalf)__expf(wv.y - cv.y);
    o[2] = (bhalf)__expf(wv.z - cv.z);
    o[3] = (bhalf)__expf(wv.w - cv.w);
    *(bhalf4*)(eA + (size_t)i * NN_ + t * 256 + l * 4) = o;
  }
}

// ---------------- GEMM: out[b,i] = log( sum_k exp(la[b,k]) * eA[i,k] ) ----------------
// 256x256 tile, BK=64, 512 thr (8 waves 2Mx4N). Round-7 pipeline, TWO barriers/tile:
//   top: 12 ds_read (af q0 + bq) -> lgkm0 -> MFMA q0
//   MID SBAR (all waves' top reads drained before it) -> STB B(t+2) into CURRENT buf
//   af q1; VMW(4) retires B(t+1)+A(t+1) -> cvt H0; MFMA q1
//   af q2; cvt H1; MFMA q2
//   af q3; LOADA A(t+2); MFMA q3
//   END SBAR (publishes cvt writes; next tile's reads follow)
// Race audit: STB overwrites B(t)'s region only after MID SBAR which orders every
// wave's bq-read drain (LGKM0 pre-MFMA q0) before any STB issue. cvt writes target
// Abuf^1, last read at tile t-1 (drained before t-1's END SBAR). No head barrier
// needed: top reads only require t-1's END SBAR.
// Steady vmcnt queue at WA: [B(t+1)4, A(t+1)8, B(t+2)4] -> VMW(4).
// LDS: A dbuf [0,64K), B dbuf [64K,128K). Both-sides XOR swizzle as rounds 2-7.

#define VMW(N)  asm volatile("s_waitcnt vmcnt(" #N ")" ::: "memory")
#define LGKM0   asm volatile("s_waitcnt lgkmcnt(0)" ::: "memory")
#define SBAR    __builtin_amdgcn_s_barrier()
#define SCB0    __builtin_amdgcn_sched_barrier(0)
#define NOPS    ((void)0)

#define STB(BUF, H, TOFF) do {                                                \
    const bhalf* g_ = pgB + (H) * 131072 + (TOFF) * 64;                       \
    unsigned char* d_ = lds + 65536 + (BUF) * 32768 + (H) * 16384 + tid * 16; \
    gload_lds16(g_, d_); gload_lds16(g_ + 65536, d_ + 8192); } while (0)

// coalesced: round r_, lanes 0..15 cover one row's 256B; rows r_*32+(tid>>4)
#define LOADA(TOFF) do {                                                      \
    _Pragma("unroll")                                                         \
    for (int r_ = 0; r_ < 8; ++r_) va[r_] = pLA4[r_ * 8192 + (TOFF) * 16];    \
  } while (0)

// exp + pack to bf16, 4x ds_write_b64 for chunk-half H (rounds 4H..4H+3)
#define CVTA_H(BUF, H) do {                                                   \
    unsigned char* d_ = dA_base + (BUF) * 32768 + (H) * 16384;                \
    _Pragma("unroll")                                                         \
    for (int j_ = 0; j_ < 4; ++j_) {                                          \
      float4 u_ = va[(H) * 4 + j_];                                           \
      bhalf4 o_;                                                              \
      o_[0] = (bhalf)__expf(u_.x); o_[1] = (bhalf)__expf(u_.y);               \
      o_[2] = (bhalf)__expf(u_.z); o_[3] = (bhalf)__expf(u_.w);               \
      *(bhalf4*)(d_ + j_ * 4096) = o_;                                        \
    } } while (0)

#define DS_AF(BUF, Q)                                                         \
  af[0][0] = *(const bhalf8*)(pA0 + (BUF) * 32768 + (Q) * 4096);              \
  af[0][1] = *(const bhalf8*)(pA1 + (BUF) * 32768 + (Q) * 4096);              \
  af[1][0] = *(const bhalf8*)(pA0 + (BUF) * 32768 + (Q) * 4096 + 2048);       \
  af[1][1] = *(const bhalf8*)(pA1 + (BUF) * 32768 + (Q) * 4096 + 2048);

#define DS_BQ(BUF)                                                            \
  _Pragma("unroll")                                                           \
  for (int n_ = 0; n_ < 4; ++n_) {                                            \
    bq[n_][0] = *(const bhalf8*)(pB0 + (BUF) * 32768 + n_ * 2048);            \
    bq[n_][1] = *(const bhalf8*)(pB1 + (BUF) * 32768 + n_ * 2048);            \
  }

#define MFMA8(Q)                                                              \
  __builtin_amdgcn_s_setprio(1);                                              \
  _Pragma("unroll")                                                           \
  for (int m_ = 0; m_ < 2; ++m_)                                              \
    _Pragma("unroll")                                                         \
    for (int n_ = 0; n_ < 4; ++n_)                                            \
      _Pragma("unroll")                                                       \
      for (int kk_ = 0; kk_ < 2; ++kk_)                                       \
        acc[2 * (Q) + m_][n_] = __builtin_amdgcn_mfma_f32_16x16x32_bf16(      \
            af[m_][kk_], bq[n_][kk_], acc[2 * (Q) + m_][n_], 0, 0, 0);        \
  __builtin_amdgcn_s_setprio(0);

// LT: A(t+2) offset rel. base (-1 none). BT: B(t+2) offset (-1 none).
// WA: wait before cvt H0 (VMW(4)/VMW(0)/NOPS). CV: cvt A(t+1) -> buf BUF^1.
#define KTILE(BUF, LT, BT, WA, CV)                                            \
  {                                                                           \
    bhalf8 bq[4][2];                                                          \
    bhalf8 af[2][2];                                                          \
    DS_AF(BUF, 0) DS_BQ(BUF)                                                  \
    SCB0; LGKM0; SCB0;                                                        \
    MFMA8(0)                                                                  \
    SCB0; SBAR;                                                               \
    if ((BT) >= 0) { STB(BUF, 0, BT); STB(BUF, 1, BT); }                      \
    DS_AF(BUF, 1)                                                             \
    WA;                                                                       \
    if (CV) CVTA_H((BUF) ^ 1, 0);                                             \
    LGKM0; SCB0;                                                              \
    MFMA8(1)                                                                  \
    DS_AF(BUF, 2)                                                             \
    if (CV) CVTA_H((BUF) ^ 1, 1);                                             \
    LGKM0; SCB0;                                                              \
    MFMA8(2)                                                                  \
    DS_AF(BUF, 3)                                                             \
    if ((LT) >= 0) LOADA(LT);                                                 \
    LGKM0; SCB0;                                                              \
    MFMA8(3)                                                                  \
    SCB0; SBAR;                                                               \
  }

__global__ __launch_bounds__(512, 2) void k_gemm(const float* __restrict__ LA, // [M][K] f32
                                                 const bhalf* __restrict__ Bt, // eA [N][K]
                                                 float* __restrict__ out) {
  __shared__ __align__(16) unsigned char lds[131072];

  const int nwg = gridDim.x;              // 256, %8==0
  const int wg  = blockIdx.x;
  const int swz = (wg & 7) * (nwg >> 3) + (wg >> 3);
  const int bm = swz >> 2;                // 0..63
  const int bn = swz & 3;                 // 0..3

  const int tid = threadIdx.x;
  const int l = tid & 63;
  const int w = tid >> 6;
  const int wr = w >> 2;                  // 0..1 (M)
  const int wc = w & 3;                   // 0..3 (N)

  // B staging geometry (gload_lds, linear dest, pre-swizzled source)
  const int r8  = tid >> 3;
  const int kel = (((tid & 7) ^ (r8 & 7)) << 3);
  const bhalf* pgB = Bt + (size_t)(bn * 256 + r8) * KK_ + kel;

  // A fused staging: coalesced. Round r_: row = r_*32 + (tid>>4), 16B chunk tid&15.
  const float4* pLA4 = (const float4*)(LA + (size_t)(bm * 256 + (tid >> 4)) * KK_) + (tid & 15);
  // write: row&7 == (tid>>4)&7 (round-invariant); chunk c=(tid&15)>>1, byte = (tid&1)*8
  unsigned char* dA_base = lds + (tid >> 4) * 128 +
                           ((((tid & 15) >> 1) ^ ((tid >> 4) & 7)) << 4) + ((tid & 1) << 3);

  // loop-invariant LDS read bases (fragment row % 8 == l % 8)
  const int kx  = 16 * (l >> 4);
  const int x16 = (l & 7) << 4;
  const int kx0 = kx ^ x16;
  const int kx1 = (64 + kx) ^ x16;
  const unsigned char* pA0 = lds + wr * 16384 + (l & 15) * 128 + kx0;
  const unsigned char* pA1 = lds + wr * 16384 + (l & 15) * 128 + kx1;
  const unsigned char* pB0 = lds + 65536 + (wc >> 1) * 16384 + ((wc & 1) * 64 + (l & 15)) * 128 + kx0;
  const unsigned char* pB1 = lds + 65536 + (wc >> 1) * 16384 + ((wc & 1) * 64 + (l & 15)) * 128 + kx1;

  f32x4 zero = {0.f, 0.f, 0.f, 0.f};
  f32x4 acc[8][4];
#pragma unroll
  for (int m = 0; m < 8; ++m)
#pragma unroll
    for (int n = 0; n < 4; ++n) acc[m][n] = zero;

  float4 va[8];

  // prologue (queue oldest->newest): A(0)8, B(0)4 -> VMW(4) retires A(0) -> cvt buf0;
  // then B(1)4, A(1)8 -> VMW(12) retires B(0). Entering tile 0: [B(1)4, A(1)8].
  LOADA(0);
  STB(0, 0, 0); STB(0, 1, 0);
  VMW(4);
  CVTA_H(0, 0); CVTA_H(0, 1);
  STB(1, 0, 1); STB(1, 1, 1);
  LOADA(1);
  VMW(12);
  LGKM0;
  SBAR;

  // tiles 0..13: 7 pairs; base advances 2 k-tiles per pair. VMW(4) uniform:
  // tile 0 queue at WA = [B(1)4, A(1)8, B(2)4] -> retires B(1)+A(1) ✓
  // steady queue    = [B(t+1)4, A(t+1)8, B(t+2)4] -> retires B(t+1)+A(t+1) ✓
  for (int p = 0; p < 7; ++p) {
    KTILE(0, 2, 2, VMW(4), 1)
    KTILE(1, 3, 3, VMW(4), 1)
    pLA4 += 32;   // 2 tiles * 16 float4
    pgB  += 128;  // 2 tiles * 64 bf16
  }
  // T14: queue = [B(15)4, A(15)8]; VMW(0) drains all; cvt A(15)->buf1
  KTILE(0, -1, -1, VMW(0), 1)
  // T15: pure compute
  KTILE(1, -1, -1, NOPS, 0)

  // epilogue: out = log(acc). D row = 4*(l>>4)+r (+16/mf), col = l&15 (+16/nf)
  const int c0 = bn * 256 + wc * 64 + (l & 15);
  const int r0 = bm * 256 + wr * 128 + (l >> 4) * 4;
#pragma unroll
  for (int mf = 0; mf < 8; ++mf) {
#pragma unroll
    for (int r = 0; r < 4; ++r) {
      const int row = r0 + mf * 16 + r;
      float* o = out + (size_t)row * NN_ + c0;
#pragma unroll
      for (int nf = 0; nf < 4; ++nf)
        o[nf * 16] = __logf(acc[mf][nf][r]);
    }
  }
}

extern "C" void kernel_launch(void* const* d_in, const int* in_sizes, int n_in,
                              void* d_out, int out_size, void* d_ws, size_t ws_size,
                              hipStream_t stream) {
  const float* log_alpha = (const float*)d_in[0];  // [16384,1024] f32
  const float* W         = (const float*)d_in[1];  // [1024,1024] f32
  float* out = (float*)d_out;                      // [16384,1024] f32

  uintptr_t ws = (uintptr_t)d_ws;
  bhalf* eA     = (bhalf*)(ws);                    // 2,097,152 B
  float* colLSE = (float*)(ws + 2097152);          //     4,096 B
  float* pM     = (float*)(ws + 2101248);          //   131,072 B
  float* pS     = (float*)(ws + 2232320);          //   131,072 B

  k_colpart<<<dim3(4, 32), 256, 0, stream>>>(W, pM, pS);
  k_colfin<<<4, 256, 0, stream>>>(pM, pS, colLSE);
  k_expA<<<NN_, 64, 0, stream>>>(W, colLSE, eA);
  k_gemm<<<(MB_ / 256) * (NN_ / 256), 512, 0, stream>>>(log_alpha, eA, out);
}

// Round 15
// 58.283 us; speedup vs baseline: 1.2324x; 1.0544x over previous
//
#include <hip/hip_runtime.h>
#include <hip/hip_bf16.h>
#include <stdint.h>

#define MB_ 16384
#define NN_ 1024
#define KK_ 1024

typedef __bf16 bhalf;
typedef __bf16 bhalf8 __attribute__((ext_vector_type(8)));
typedef __bf16 bhalf4 __attribute__((ext_vector_type(4)));
typedef float f32x4 __attribute__((ext_vector_type(4)));

typedef const __attribute__((address_space(1))) void* gas_ptr;
typedef __attribute__((address_space(3))) void* las_ptr;

__device__ __forceinline__ void gload_lds16(const void* g, void* l) {
  __builtin_amdgcn_global_load_lds((gas_ptr)g, (las_ptr)l, 16, 0, 0);
}

// ---------------- K1a: partial column max / sumexp (over rows, per column) ----------------
__global__ void k_colpart(const float* __restrict__ W,
                          float* __restrict__ pM, float* __restrict__ pS) {
  int col = blockIdx.x * 256 + threadIdx.x;
  int rc  = blockIdx.y;
  const float* p = W + (size_t)rc * 32 * NN_ + col;
  float v[32];
#pragma unroll
  for (int i = 0; i < 32; ++i) v[i] = p[(size_t)i * NN_];
  float m = v[0];
#pragma unroll
  for (int i = 1; i < 32; ++i) m = fmaxf(m, v[i]);
  float s = 0.f;
#pragma unroll
  for (int i = 0; i < 32; ++i) s += __expf(v[i] - m);
  pM[rc * NN_ + col] = m;
  pS[rc * NN_ + col] = s;
}

// ---------------- K1b: combine partials -> colLSE ----------------
__global__ void k_colfin(const float* __restrict__ pM, const float* __restrict__ pS,
                         float* __restrict__ colLSE) {
  int col = blockIdx.x * 256 + threadIdx.x;
  float m = -1e30f;
#pragma unroll
  for (int i = 0; i < 32; ++i) m = fmaxf(m, pM[i * NN_ + col]);
  float s = 0.f;
#pragma unroll
  for (int i = 0; i < 32; ++i) s += pS[i * NN_ + col] * __expf(pM[i * NN_ + col] - m);
  colLSE[col] = m + __logf(s);
}

// ---------------- K2: eA[i,k] = exp(W[i,k]-colLSE[k]) ----------------
__global__ void k_expA(const float* __restrict__ W, const float* __restrict__ colLSE,
                       bhalf* __restrict__ eA) {
  int i = blockIdx.x;
  int l = threadIdx.x;
  const float4* row = (const float4*)(W + (size_t)i * NN_);
  const float4* cls = (const float4*)colLSE;
#pragma unroll
  for (int t = 0; t < 4; ++t) {
    float4 wv = row[t * 64 + l];
    float4 cv = cls[t * 64 + l];
    bhalf4 o;
    o[0] = (bhalf)__expf(wv.x - cv.x);
    o[1] = (bhalf)__expf(wv.y - cv.y);
    o[2] = (bhalf)__expf(wv.z - cv.z);
    o[3] = (bhalf)__expf(wv.w - cv.w);
    *(bhalf4*)(eA + (size_t)i * NN_ + t * 256 + l * 4) = o;
  }
}

// ---------------- GEMM: out[b,i] = log( sum_k exp(la[b,k]) * eA[i,k] ) ----------------
// 256x256 tile, BK=64, 512 thr (8 waves 2Mx4N). Round-11 schedule; LOADA moved to
// q2-post-cvt (va dead there) for ~3-batch A-latency cover:
//   top: 12 ds_read (af q0 + bq) -> lgkm0 -> MFMA q0
//   MID SBAR -> STB B(t+2) -> af q1; VMW(4) retires B(t+1)+A(t+1) -> cvt H0; MFMA q1
//   af q2; cvt H1; LOADA A(t+2); MFMA q2
//   af q3; MFMA q3; END SBAR
// Steady queue at VMW(4): [B(t+1)4, A(t+1)8, B(t+2)4] -> retires B(t+1)+A(t+1).
// A(t+2) cover: q2(t) -> q1(t+1) ~ 3 MFMA batches (~1800 cyc) > HBM ~900 cyc.
// LDS: A dbuf [0,64K), B dbuf [64K,128K). Both-sides XOR swizzle as rounds 2-11.

#define VMW(N)  asm volatile("s_waitcnt vmcnt(" #N ")" ::: "memory")
#define LGKM0   asm volatile("s_waitcnt lgkmcnt(0)" ::: "memory")
#define SBAR    __builtin_amdgcn_s_barrier()
#define SCB0    __builtin_amdgcn_sched_barrier(0)
#define NOPS    ((void)0)

#define STB(BUF, H, TOFF) do {                                                \
    const bhalf* g_ = pgB + (H) * 131072 + (TOFF) * 64;                       \
    unsigned char* d_ = lds + 65536 + (BUF) * 32768 + (H) * 16384 + tid * 16; \
    gload_lds16(g_, d_); gload_lds16(g_ + 65536, d_ + 8192); } while (0)

// coalesced: round r_, lanes 0..15 cover one row's 256B; rows r_*32+(tid>>4)
#define LOADA(TOFF) do {                                                      \
    _Pragma("unroll")                                                         \
    for (int r_ = 0; r_ < 8; ++r_) va[r_] = pLA4[r_ * 8192 + (TOFF) * 16];    \
  } while (0)

// exp + pack to bf16, 4x ds_write_b64 for chunk-half H (rounds 4H..4H+3)
#define CVTA_H(BUF, H) do {                                                   \
    unsigned char* d_ = dA_base + (BUF) * 32768 + (H) * 16384;                \
    _Pragma("unroll")                                                         \
    for (int j_ = 0; j_ < 4; ++j_) {                                          \
      float4 u_ = va[(H) * 4 + j_];                                           \
      bhalf4 o_;                                                              \
      o_[0] = (bhalf)__expf(u_.x); o_[1] = (bhalf)__expf(u_.y);               \
      o_[2] = (bhalf)__expf(u_.z); o_[3] = (bhalf)__expf(u_.w);               \
      *(bhalf4*)(d_ + j_ * 4096) = o_;                                        \
    } } while (0)

#define DS_AF(BUF, Q)                                                         \
  af[0][0] = *(const bhalf8*)(pA0 + (BUF) * 32768 + (Q) * 4096);              \
  af[0][1] = *(const bhalf8*)(pA1 + (BUF) * 32768 + (Q) * 4096);              \
  af[1][0] = *(const bhalf8*)(pA0 + (BUF) * 32768 + (Q) * 4096 + 2048);       \
  af[1][1] = *(const bhalf8*)(pA1 + (BUF) * 32768 + (Q) * 4096 + 2048);

#define DS_BQ(BUF)                                                            \
  _Pragma("unroll")                                                           \
  for (int n_ = 0; n_ < 4; ++n_) {                                            \
    bq[n_][0] = *(const bhalf8*)(pB0 + (BUF) * 32768 + n_ * 2048);            \
    bq[n_][1] = *(const bhalf8*)(pB1 + (BUF) * 32768 + n_ * 2048);            \
  }

#define MFMA8(Q)                                                              \
  __builtin_amdgcn_s_setprio(1);                                              \
  _Pragma("unroll")                                                           \
  for (int m_ = 0; m_ < 2; ++m_)                                              \
    _Pragma("unroll")                                                         \
    for (int n_ = 0; n_ < 4; ++n_)                                            \
      _Pragma("unroll")                                                       \
      for (int kk_ = 0; kk_ < 2; ++kk_)                                       \
        acc[2 * (Q) + m_][n_] = __builtin_amdgcn_mfma_f32_16x16x32_bf16(      \
            af[m_][kk_], bq[n_][kk_], acc[2 * (Q) + m_][n_], 0, 0, 0);        \
  __builtin_amdgcn_s_setprio(0);

// LT: A(t+2) offset rel. base (-1 none). BT: B(t+2) offset (-1 none).
// WA: wait before cvt H0 (VMW(4)/VMW(0)/NOPS). CV: cvt A(t+1) -> buf BUF^1.
#define KTILE(BUF, LT, BT, WA, CV)                                            \
  {                                                                           \
    bhalf8 bq[4][2];                                                          \
    bhalf8 af[2][2];                                                          \
    DS_AF(BUF, 0) DS_BQ(BUF)                                                  \
    SCB0; LGKM0; SCB0;                                                        \
    MFMA8(0)                                                                  \
    SCB0; SBAR;                                                               \
    if ((BT) >= 0) { STB(BUF, 0, BT); STB(BUF, 1, BT); }                      \
    DS_AF(BUF, 1)                                                             \
    WA;                                                                       \
    if (CV) CVTA_H((BUF) ^ 1, 0);                                             \
    LGKM0; SCB0;                                                              \
    MFMA8(1)                                                                  \
    DS_AF(BUF, 2)                                                             \
    if (CV) CVTA_H((BUF) ^ 1, 1);                                             \
    if ((LT) >= 0) LOADA(LT);                                                 \
    LGKM0; SCB0;                                                              \
    MFMA8(2)                                                                  \
    DS_AF(BUF, 3)                                                             \
    LGKM0; SCB0;                                                              \
    MFMA8(3)                                                                  \
    SCB0; SBAR;                                                               \
  }

__global__ __launch_bounds__(512, 2) void k_gemm(const float* __restrict__ LA, // [M][K] f32
                                                 const bhalf* __restrict__ Bt, // eA [N][K]
                                                 float* __restrict__ out) {
  __shared__ __align__(16) unsigned char lds[131072];

  const int nwg = gridDim.x;              // 256, %8==0
  const int wg  = blockIdx.x;
  const int swz = (wg & 7) * (nwg >> 3) + (wg >> 3);
  const int bm = swz >> 2;                // 0..63
  const int bn = swz & 3;                 // 0..3

  const int tid = threadIdx.x;
  const int l = tid & 63;
  const int w = tid >> 6;
  const int wr = w >> 2;                  // 0..1 (M)
  const int wc = w & 3;                   // 0..3 (N)

  // B staging geometry (gload_lds, linear dest, pre-swizzled source)
  const int r8  = tid >> 3;
  const int kel = (((tid & 7) ^ (r8 & 7)) << 3);
  const bhalf* pgB = Bt + (size_t)(bn * 256 + r8) * KK_ + kel;

  // A fused staging: coalesced. Round r_: row = r_*32 + (tid>>4), 16B chunk tid&15.
  const float4* pLA4 = (const float4*)(LA + (size_t)(bm * 256 + (tid >> 4)) * KK_) + (tid & 15);
  // write: row&7 == (tid>>4)&7 (round-invariant); chunk c=(tid&15)>>1, byte = (tid&1)*8
  unsigned char* dA_base = lds + (tid >> 4) * 128 +
                           ((((tid & 15) >> 1) ^ ((tid >> 4) & 7)) << 4) + ((tid & 1) << 3);

  // loop-invariant LDS read bases (fragment row % 8 == l % 8)
  const int kx  = 16 * (l >> 4);
  const int x16 = (l & 7) << 4;
  const int kx0 = kx ^ x16;
  const int kx1 = (64 + kx) ^ x16;
  const unsigned char* pA0 = lds + wr * 16384 + (l & 15) * 128 + kx0;
  const unsigned char* pA1 = lds + wr * 16384 + (l & 15) * 128 + kx1;
  const unsigned char* pB0 = lds + 65536 + (wc >> 1) * 16384 + ((wc & 1) * 64 + (l & 15)) * 128 + kx0;
  const unsigned char* pB1 = lds + 65536 + (wc >> 1) * 16384 + ((wc & 1) * 64 + (l & 15)) * 128 + kx1;

  f32x4 zero = {0.f, 0.f, 0.f, 0.f};
  f32x4 acc[8][4];
#pragma unroll
  for (int m = 0; m < 8; ++m)
#pragma unroll
    for (int n = 0; n < 4; ++n) acc[m][n] = zero;

  float4 va[8];

  // prologue (queue oldest->newest): A(0)8, B(0)4 -> VMW(4) retires A(0) -> cvt buf0;
  // then B(1)4, A(1)8 -> VMW(12) retires B(0). Entering tile 0: [B(1)4, A(1)8].
  LOADA(0);
  STB(0, 0, 0); STB(0, 1, 0);
  VMW(4);
  CVTA_H(0, 0); CVTA_H(0, 1);
  STB(1, 0, 1); STB(1, 1, 1);
  LOADA(1);
  VMW(12);
  LGKM0;
  SBAR;

  // tiles 0..13: 7 pairs; base advances 2 k-tiles per pair. VMW(4) uniform:
  // tile 0 queue at WA = [B(1)4, A(1)8, B(2)4] -> retires B(1)+A(1) ✓
  // steady queue    = [B(t+1)4, A(t+1)8, B(t+2)4] -> retires B(t+1)+A(t+1) ✓
  for (int p = 0; p < 7; ++p) {
    KTILE(0, 2, 2, VMW(4), 1)
    KTILE(1, 3, 3, VMW(4), 1)
    pLA4 += 32;   // 2 tiles * 16 float4
    pgB  += 128;  // 2 tiles * 64 bf16
  }
  // T14: queue = [B(15)4, A(15)8]; VMW(0) drains all; cvt A(15)->buf1
  KTILE(0, -1, -1, VMW(0), 1)
  // T15: pure compute
  KTILE(1, -1, -1, NOPS, 0)

  // epilogue: out = log(acc). D row = 4*(l>>4)+r (+16/mf), col = l&15 (+16/nf)
  const int c0 = bn * 256 + wc * 64 + (l & 15);
  const int r0 = bm * 256 + wr * 128 + (l >> 4) * 4;
#pragma unroll
  for (int mf = 0; mf < 8; ++mf) {
#pragma unroll
    for (int r = 0; r < 4; ++r) {
      const int row = r0 + mf * 16 + r;
      float* o = out + (size_t)row * NN_ + c0;
#pragma unroll
      for (int nf = 0; nf < 4; ++nf)
        o[nf * 16] = __logf(acc[mf][nf][r]);
    }
  }
}

extern "C" void kernel_launch(void* const* d_in, const int* in_sizes, int n_in,
                              void* d_out, int out_size, void* d_ws, size_t ws_size,
                              hipStream_t stream) {
  const float* log_alpha = (const float*)d_in[0];  // [16384,1024] f32
  const float* W         = (const float*)d_in[1];  // [1024,1024] f32
  float* out = (float*)d_out;                      // [16384,1024] f32

  uintptr_t ws = (uintptr_t)d_ws;
  bhalf* eA     = (bhalf*)(ws);                    // 2,097,152 B
  float* colLSE = (float*)(ws + 2097152);          //     4,096 B
  float* pM     = (float*)(ws + 2101248);          //   131,072 B
  float* pS     = (float*)(ws + 2232320);          //   131,072 B

  k_colpart<<<dim3(4, 32), 256, 0, stream>>>(W, pM, pS);
  k_colfin<<<4, 256, 0, stream>>>(pM, pS, colLSE);
  k_expA<<<NN_, 64, 0, stream>>>(W, colLSE, eA);
  k_gemm<<<(MB_ / 256) * (NN_ / 256), 512, 0, stream>>>(log_alpha, eA, out);
}